// Round 8
// baseline (267.452 us; speedup 1.0000x reference)
//
#include <hip/hip_runtime.h>
#include <hip/hip_bf16.h>

#define TOKENS 2048
#define DIM 512
#define NEXP 16
#define HID 2048
#define CAP 320                 /* rows per expert (mean 256, +4 sigma margin) */
#define NTPE (CAP / 64)         /* 5 m-tiles per expert */
#define MTILES (NEXP * NTPE)    /* 80 */
#define NROWS (NEXP * CAP)      /* 5120 */

typedef unsigned short ushort_t;
typedef __attribute__((ext_vector_type(8))) __bf16 bf16x8;
typedef __attribute__((ext_vector_type(4))) float f32x4;

// workspace byte offsets (total 90,260,480 <= known-good 90.3MB)
#define OFF_CNT 0
#define OFF_LTOK 1024
#define OFF_LW 21504
#define OFF_S1 41984
#define OFF_S2 62464
#define OFF_XBF 82944        /* 2048*512*2 = 2,097,152 -> ends 2,180,096 */
#define OFF_H 2180096        /* 5120*2048*2 = 20,971,520 -> ends 23,151,616 */
#define OFF_W1T 23151616     /* 33,554,432 -> ends 56,706,048 */
#define OFF_W2T 56706048     /* 33,554,432 -> ends 90,260,480 */

__device__ __forceinline__ ushort_t f2b(float f) {
  __bf16 b = (__bf16)f;
  return __builtin_bit_cast(unsigned short, b);
}
__device__ __forceinline__ float b2f(ushort_t u) {
  return __builtin_bit_cast(float, (unsigned)u << 16);
}

// =============== K1: router (blocks 0..63) + W1 convert (64..4159) ==========
// W1 convert: src[E][512][2048] f32 -> W1t tiled [E][N/16][K/32][512] bf16,
// tile elem = n_local*32 + k_local (R4 no-LDS form, transpose via loads).
__global__ __launch_bounds__(256) void pre_k(
    const float* __restrict__ x, const float* __restrict__ Wg,
    const float* __restrict__ W1, ushort_t* __restrict__ xbf,
    int* __restrict__ counts, int* __restrict__ ltok, float* __restrict__ lw,
    float* __restrict__ s1, float* __restrict__ s2, float* __restrict__ out,
    ushort_t* __restrict__ W1t) {
  int bid = blockIdx.x;
  int t = threadIdx.x;
  if (bid >= 64) {
    // ---- W1 conversion ----
    int idx = bid - 64;
    int bx = idx & 255, e = idx >> 8;
    int bn = bx & 31, bk = bx >> 5;      /* N=2048 -> 32 bn; K=512 -> 8 bk */
    const int K = DIM, N = HID;
    int w = t >> 6, l = t & 63;
    int n = bn * 64 + l;
    int k_base = bk * 64, kt0 = k_base >> 5, kk = w * 8;
    const float* sp = W1 + ((size_t)e * K + k_base + kk) * N + n;
    float v[16];
#pragma unroll
    for (int j = 0; j < 8; j++) v[j] = sp[(size_t)j * N];
#pragma unroll
    for (int j = 0; j < 8; j++) v[8 + j] = sp[(size_t)(32 + j) * N];
    size_t tb = ((size_t)(e * (N >> 4) + (n >> 4)) * (K >> 5) + kt0) * 512 +
                (n & 15) * 32 + kk;
    union { ushort_t u[8]; uint4 q; } s0, s1u;
#pragma unroll
    for (int j = 0; j < 8; j++) { s0.u[j] = f2b(v[j]); s1u.u[j] = f2b(v[8 + j]); }
    *(uint4*)(W1t + tb) = s0.q;
    *(uint4*)(W1t + tb + 512) = s1u.q;
    return;
  }

  // ---- router ----
  {
    float4 z = {0.f, 0.f, 0.f, 0.f};
    float4* o4 = (float4*)out + bid * 4096 + t;
#pragma unroll
    for (int i = 0; i < 16; i++) o4[i * 256] = z;
  }
  {
    int idx = bid * 256 + t;
    if (idx < NROWS) { s1[idx] = 0.f; s2[idx] = 0.f; }
  }

  __shared__ float xs[4][512];
  __shared__ float lg[4][16];
  __shared__ int lcnt[NEXP];
  __shared__ int ltoks[NEXP][64];
  __shared__ float lws[NEXP][64];
  __shared__ int base_s[NEXP];

  if (t < NEXP) lcnt[t] = 0;
  __syncthreads();

  int lane = t & 63, w = t >> 6;
  int dq = lane >> 2, e4 = lane & 3;
  const float* wgp = Wg + dq * NEXP + e4 * 4;

  for (int it = 0; it < 8; it++) {
    int tok = bid * 32 + w * 8 + it;
    const float* xr = x + (size_t)tok * DIM + lane * 8;
    float4 xa = *(const float4*)xr;
    float4 xb = *(const float4*)(xr + 4);
    union { ushort_t u[8]; uint4 v; } pk;
    pk.u[0] = f2b(xa.x); pk.u[1] = f2b(xa.y); pk.u[2] = f2b(xa.z); pk.u[3] = f2b(xa.w);
    pk.u[4] = f2b(xb.x); pk.u[5] = f2b(xb.y); pk.u[6] = f2b(xb.z); pk.u[7] = f2b(xb.w);
    *(uint4*)(xbf + (size_t)tok * DIM + lane * 8) = pk.v;
    *(float4*)&xs[w][lane * 8] = xa;
    *(float4*)&xs[w][lane * 8 + 4] = xb;

    float4 a = {0.f, 0.f, 0.f, 0.f};
#pragma unroll
    for (int kk = 0; kk < 32; kk++) {
      float xv = xs[w][kk * 16 + dq];
      float4 g = *(const float4*)(wgp + kk * 16 * NEXP);
      a.x += xv * g.x; a.y += xv * g.y; a.z += xv * g.z; a.w += xv * g.w;
    }
#pragma unroll
    for (int off = 32; off >= 4; off >>= 1) {
      a.x += __shfl_down(a.x, off);
      a.y += __shfl_down(a.y, off);
      a.z += __shfl_down(a.z, off);
      a.w += __shfl_down(a.w, off);
    }
    if (lane < 4) *(float4*)&lg[w][lane * 4] = a;
    if (lane == 0) {
      int i0 = 0;
      float v0 = lg[w][0];
#pragma unroll
      for (int e = 1; e < NEXP; e++)
        if (lg[w][e] > v0) { v0 = lg[w][e]; i0 = e; }
      int i1 = -1;
      float v1 = -3.4e38f;
#pragma unroll
      for (int e = 0; e < NEXP; e++)
        if (e != i0 && lg[w][e] > v1) { v1 = lg[w][e]; i1 = e; }
      float ex = __expf(v1 - v0);
      float w0 = 1.f / (1.f + ex);
      int p0 = atomicAdd(&lcnt[i0], 1);
      ltoks[i0][p0] = tok;
      lws[i0][p0] = w0;
      int p1 = atomicAdd(&lcnt[i1], 1);
      ltoks[i1][p1] = tok;
      lws[i1][p1] = ex / (1.f + ex);
    }
  }
  __syncthreads();
  if (t < NEXP) base_s[t] = atomicAdd(&counts[t], lcnt[t]);
  __syncthreads();
  int e = t >> 4, i0 = t & 15;
  int n = lcnt[e], b = base_s[e];
  for (int i = i0; i < n; i += 16) {
    int slot = b + i;
    if (slot < CAP) {
      ltok[e * CAP + slot] = ltoks[e][i];
      lw[e * CAP + slot] = lws[e][i];
    }
  }
}

// ====== K2: ffn1 (blocks 0..639, R4 form) + W2 convert (640..4735) ==========
// ffn1: h = silu(x @ W1 + b1) -> hbuf row-major bf16 + row stats.
// W1t tiled [E][HID/16][DIM/32][512]; frag = base + nb*8192 + ks*512 + ...
__global__ __launch_bounds__(256) void mid_k(
    const ushort_t* __restrict__ W1t, const float* __restrict__ b1,
    const int* __restrict__ counts, const int* __restrict__ ltok,
    const ushort_t* __restrict__ xbf, ushort_t* __restrict__ hbuf,
    float* __restrict__ s1, float* __restrict__ s2,
    const float* __restrict__ W2, ushort_t* __restrict__ W2t) {
  int bid = blockIdx.x;
  int t = threadIdx.x;
  if (bid >= 640) {
    // ---- W2 conversion ----
    int idx = bid - 640;
    int bx = idx & 255, e = idx >> 8;
    int bn = bx & 7, bk = bx >> 3;       /* N=512 -> 8 bn; K=2048 -> 32 bk */
    const int K = HID, N = DIM;
    int w = t >> 6, l = t & 63;
    int n = bn * 64 + l;
    int k_base = bk * 64, kt0 = k_base >> 5, kk = w * 8;
    const float* sp = W2 + ((size_t)e * K + k_base + kk) * N + n;
    float v[16];
#pragma unroll
    for (int j = 0; j < 8; j++) v[j] = sp[(size_t)j * N];
#pragma unroll
    for (int j = 0; j < 8; j++) v[8 + j] = sp[(size_t)(32 + j) * N];
    size_t tb = ((size_t)(e * (N >> 4) + (n >> 4)) * (K >> 5) + kt0) * 512 +
                (n & 15) * 32 + kk;
    union { ushort_t u[8]; uint4 q; } s0, s1u;
#pragma unroll
    for (int j = 0; j < 8; j++) { s0.u[j] = f2b(v[j]); s1u.u[j] = f2b(v[8 + j]); }
    *(uint4*)(W2t + tb) = s0.q;
    *(uint4*)(W2t + tb + 512) = s1u.q;
    return;
  }

  // ---- ffn1 ----
  int xb = bid % 80;
  int e = xb / NTPE, mt = xb % NTPE;
  int cnt = counts[e];
  if (cnt - mt * 64 <= 0) return;
  int row0 = e * CAP + mt * 64;
  int h0 = (bid / 80) * 256;

  __shared__ __align__(16) ushort_t As[2][64 * 40];

  int lane = t & 63, wave = t >> 6;
  int quad = lane >> 4, l16 = lane & 15;

  int sr = t >> 2, sp = t & 3;
  int stok = ltok[row0 + sr];
  bool sok = (unsigned)stok < TOKENS;
  const ushort_t* sx = xbf + (size_t)(sok ? stok : 0) * DIM + sp * 8;

  int ncol = h0 + wave * 64 + l16;
  const ushort_t* bb = W1t +
      ((size_t)(e * 128 + (h0 >> 4) + wave * 4) * 16) * 512 + l16 * 32 + quad * 8;

  f32x4 acc[4][4];
#pragma unroll
  for (int a = 0; a < 4; a++)
#pragma unroll
    for (int b = 0; b < 4; b++) acc[a][b] = {0.f, 0.f, 0.f, 0.f};

  // prologue: A(0) -> LDS[0], A(1) in regs, B(0) in regs
  uint4 avB = {0u, 0u, 0u, 0u};
  {
    uint4 avA = {0u, 0u, 0u, 0u};
    if (sok) {
      avA = *(const uint4*)(sx);
      avB = *(const uint4*)(sx + 32);
    }
    *(uint4*)(&As[0][sr * 40 + sp * 8]) = avA;
  }
  bf16x8 bc[4];
#pragma unroll
  for (int nb = 0; nb < 4; nb++)
    bc[nb] = *(const bf16x8*)(bb + nb * 8192);

#pragma unroll
  for (int ks = 0; ks < 16; ks++) {
    __syncthreads();  // LDS[ks&1] ready
    bf16x8 bn[4];
    if (ks < 15) {
#pragma unroll
      for (int nb = 0; nb < 4; nb++)
        bn[nb] = *(const bf16x8*)(bb + nb * 8192 + (ks + 1) * 512);
    }
    uint4 avN = {0u, 0u, 0u, 0u};
    if (ks < 14 && sok) avN = *(const uint4*)(sx + (ks + 2) * 32);

    bf16x8 af[4];
#pragma unroll
    for (int mb = 0; mb < 4; mb++)
      af[mb] = *(const bf16x8*)(&As[ks & 1][(mb * 16 + l16) * 40 + quad * 8]);
#pragma unroll
    for (int mb = 0; mb < 4; mb++)
#pragma unroll
      for (int nb = 0; nb < 4; nb++)
        acc[mb][nb] = __builtin_amdgcn_mfma_f32_16x16x32_bf16(af[mb], bc[nb], acc[mb][nb], 0, 0, 0);

    if (ks < 15) {
      *(uint4*)(&As[(ks + 1) & 1][sr * 40 + sp * 8]) = avB;
      avB = avN;
#pragma unroll
      for (int nb = 0; nb < 4; nb++) bc[nb] = bn[nb];
    }
  }

  float bia[4];
#pragma unroll
  for (int nb = 0; nb < 4; nb++) bia[nb] = b1[e * HID + ncol + nb * 16];
#pragma unroll
  for (int mb = 0; mb < 4; mb++) {
#pragma unroll
    for (int i = 0; i < 4; i++) {
      int m = mb * 16 + quad * 4 + i;
      size_t rowg = (size_t)(row0 + m);
      float ps = 0.f, qs = 0.f;
#pragma unroll
      for (int nb = 0; nb < 4; nb++) {
        float v = acc[mb][nb][i] + bia[nb];
        v = v / (1.f + __expf(-v));
        hbuf[rowg * HID + ncol + nb * 16] = f2b(v);
        ps += v;
        qs += v * v;
      }
      ps += __shfl_down(ps, 8); qs += __shfl_down(qs, 8);
      ps += __shfl_down(ps, 4); qs += __shfl_down(qs, 4);
      ps += __shfl_down(ps, 2); qs += __shfl_down(qs, 2);
      ps += __shfl_down(ps, 1); qs += __shfl_down(qs, 1);
      if (l16 == 0) {
        atomicAdd(&s1[rowg], ps);
        atomicAdd(&s2[rowg], qs);
      }
    }
  }
}

// ---------------- GEMM2: out[t] += w * (LN(h) @ W2 + b2) --------------------
// R4 form but K split in FOUR via blockIdx.z (grid 80x2x4 = 640 blocks,
// ~2.5 blocks/CU, vs 320 = 1.25 before: ffn2 was grid/occupancy-limited).
// W2t tiled [E][DIM/16][HID/32][512]; LDS double-buffered pipelined.
__global__ __launch_bounds__(256) void ffn2_k(
    const ushort_t* __restrict__ W2t, const float* __restrict__ b2,
    const float* __restrict__ lng, const float* __restrict__ lnb,
    const int* __restrict__ counts, const int* __restrict__ ltok,
    const float* __restrict__ lw, const ushort_t* __restrict__ hbuf,
    const float* __restrict__ s1, const float* __restrict__ s2,
    float* __restrict__ out) {
  int e = blockIdx.x / NTPE, mt = blockIdx.x % NTPE;
  int cnt = counts[e];
  int valid = cnt - mt * 64;
  if (valid <= 0) return;
  valid = valid > 64 ? 64 : valid;
  int row0 = e * CAP + mt * 64;
  int n0 = blockIdx.y * 256;
  int kbeg = blockIdx.z * (HID / 4);     /* 512 K-elems per z */

  __shared__ __align__(16) ushort_t As[2][64 * 40];
  __shared__ float Gs[512];
  __shared__ float Cs[512];

  int t = threadIdx.x;
  int lane = t & 63, wave = t >> 6;
  int quad = lane >> 4, l16 = lane & 15;

  // stage gamma/beta slice once (512 floats each)
  if (t < 128) {
    *(float4*)&Gs[t * 4] = *(const float4*)(lng + (size_t)e * HID + kbeg + t * 4);
    *(float4*)&Cs[t * 4] = *(const float4*)(lnb + (size_t)e * HID + kbeg + t * 4);
  }

  int sr = t >> 2, sp = t & 3;
  size_t srow = (size_t)(row0 + sr);
  const ushort_t* hr = hbuf + srow * HID + kbeg + sp * 8;
  float smu = s1[srow] * (1.f / HID);
  float var = s2[srow] * (1.f / HID) - smu * smu;
  float srs = rsqrtf(var + 1e-5f);

  int ncol = n0 + wave * 64 + l16;
  const ushort_t* bb = W2t +
      ((size_t)(e * 32 + (n0 >> 4) + wave * 4) * 64 + blockIdx.z * 16) * 512 +
      l16 * 32 + quad * 8;

  f32x4 acc[4][4];
#pragma unroll
  for (int a = 0; a < 4; a++)
#pragma unroll
    for (int b = 0; b < 4; b++) acc[a][b] = {0.f, 0.f, 0.f, 0.f};

  uint4 hvA = *(const uint4*)(hr);
  uint4 hvB = *(const uint4*)(hr + 32);
  __syncthreads();  // Gs/Cs ready

  // process step0 -> LDS[0]
  {
    union { uint4 v; ushort_t u[8]; } hv;
    hv.v = hvA;
    int sb = sp * 8;
    union { ushort_t u[8]; uint4 v; } pk;
#pragma unroll
    for (int j = 0; j < 8; j++) {
      float f = (b2f(hv.u[j]) - smu) * srs;
      pk.u[j] = f2b(f * Gs[sb + j] + Cs[sb + j]);
    }
    *(uint4*)(&As[0][sr * 40 + sp * 8]) = pk.v;
  }
  bf16x8 bc[4];
#pragma unroll
  for (int nb = 0; nb < 4; nb++)
    bc[nb] = *(const bf16x8*)(bb + nb * 32768);

#pragma unroll 8
  for (int ks = 0; ks < 16; ks++) {
    __syncthreads();  // LDS[ks&1] ready
    bf16x8 bn[4];
    if (ks < 15) {
#pragma unroll
      for (int nb = 0; nb < 4; nb++)
        bn[nb] = *(const bf16x8*)(bb + nb * 32768 + (ks + 1) * 512);
    }
    uint4 hvN = {0u, 0u, 0u, 0u};
    if (ks < 14) hvN = *(const uint4*)(hr + (ks + 2) * 32);

    bf16x8 af[4];
#pragma unroll
    for (int mb = 0; mb < 4; mb++)
      af[mb] = *(const bf16x8*)(&As[ks & 1][(mb * 16 + l16) * 40 + quad * 8]);
#pragma unroll
    for (int mb = 0; mb < 4; mb++)
#pragma unroll
      for (int nb = 0; nb < 4; nb++)
        acc[mb][nb] = __builtin_amdgcn_mfma_f32_16x16x32_bf16(af[mb], bc[nb], acc[mb][nb], 0, 0, 0);

    if (ks < 15) {
      union { uint4 v; ushort_t u[8]; } hv;
      hv.v = hvB;
      int sb = (ks + 1) * 32 + sp * 8;
      union { ushort_t u[8]; uint4 v; } pk;
#pragma unroll
      for (int j = 0; j < 8; j++) {
        float f = (b2f(hv.u[j]) - smu) * srs;
        pk.u[j] = f2b(f * Gs[sb + j] + Cs[sb + j]);
      }
      *(uint4*)(&As[(ks + 1) & 1][sr * 40 + sp * 8]) = pk.v;
      hvB = hvN;
#pragma unroll
      for (int nb = 0; nb < 4; nb++) bc[nb] = bn[nb];
    }
  }

  bool addb = (blockIdx.z == 0);
  float bia[4];
#pragma unroll
  for (int nb = 0; nb < 4; nb++)
    bia[nb] = addb ? b2[e * DIM + ncol + nb * 16] : 0.f;
#pragma unroll
  for (int mb = 0; mb < 4; mb++) {
#pragma unroll
    for (int i = 0; i < 4; i++) {
      int m = mb * 16 + quad * 4 + i;
      if (m < valid) {
        int tok = ltok[row0 + m];
        float w = lw[row0 + m];
#pragma unroll
        for (int nb = 0; nb < 4; nb++) {
          float v = acc[mb][nb][i] + bia[nb];
          atomicAdd(out + (size_t)tok * DIM + ncol + nb * 16, w * v);
        }
      }
    }
  }
}

extern "C" void kernel_launch(void* const* d_in, const int* in_sizes, int n_in,
                              void* d_out, int out_size, void* d_ws, size_t ws_size,
                              hipStream_t stream) {
  const float* x = (const float*)d_in[0];
  const float* Wg = (const float*)d_in[1];
  const float* W1 = (const float*)d_in[2];
  const float* b1 = (const float*)d_in[3];
  const float* lng = (const float*)d_in[4];
  const float* lnb = (const float*)d_in[5];
  const float* W2 = (const float*)d_in[6];
  const float* b2 = (const float*)d_in[7];
  float* out = (float*)d_out;

  char* ws = (char*)d_ws;
  int* counts = (int*)(ws + OFF_CNT);
  int* ltok = (int*)(ws + OFF_LTOK);
  float* lw = (float*)(ws + OFF_LW);
  float* s1 = (float*)(ws + OFF_S1);
  float* s2 = (float*)(ws + OFF_S2);
  ushort_t* xbf = (ushort_t*)(ws + OFF_XBF);
  ushort_t* hbuf = (ushort_t*)(ws + OFF_H);
  ushort_t* W1t = (ushort_t*)(ws + OFF_W1T);
  ushort_t* W2t = (ushort_t*)(ws + OFF_W2T);

  hipMemsetAsync(counts, 0, NEXP * sizeof(int), stream);
  pre_k<<<64 + 4096, 256, 0, stream>>>(x, Wg, W1, xbf, counts, ltok, lw,
                                       s1, s2, out, W1t);
  mid_k<<<640 + 4096, 256, 0, stream>>>(W1t, b1, counts, ltok, xbf, hbuf,
                                        s1, s2, W2, W2t);
  ffn2_k<<<dim3(MTILES, DIM / 256, 4), 256, 0, stream>>>(W2t, b2, lng, lnb,
                                                         counts, ltok, lw,
                                                         hbuf, s1, s2, out);
}

// Round 9
// 246.236 us; speedup vs baseline: 1.0862x; 1.0862x over previous
//
#include <hip/hip_runtime.h>
#include <hip/hip_bf16.h>

#define TOKENS 2048
#define DIM 512
#define NEXP 16
#define HID 2048
#define CAP 320                 /* rows per expert (mean 256, +4 sigma margin) */
#define NTPE (CAP / 64)         /* 5 m-tiles per expert */
#define MTILES (NEXP * NTPE)    /* 80 */
#define NROWS (NEXP * CAP)      /* 5120 */

typedef unsigned short ushort_t;
typedef __attribute__((ext_vector_type(8))) __bf16 bf16x8;
typedef __attribute__((ext_vector_type(4))) float f32x4;

// workspace byte offsets (total 90,260,480 <= known-good 90.3MB)
#define OFF_CNT 0
#define OFF_LTOK 1024
#define OFF_LW 21504
#define OFF_S1 41984
#define OFF_S2 62464
#define OFF_XBF 82944        /* 2048*512*2 = 2,097,152 -> ends 2,180,096 */
#define OFF_H 2180096        /* 5120*2048*2 = 20,971,520 -> ends 23,151,616 */
#define OFF_W1T 23151616     /* 33,554,432 -> ends 56,706,048 */
#define OFF_W2T 56706048     /* 33,554,432 -> ends 90,260,480 */

__device__ __forceinline__ ushort_t f2b(float f) {
  __bf16 b = (__bf16)f;
  return __builtin_bit_cast(unsigned short, b);
}
__device__ __forceinline__ float b2f(ushort_t u) {
  return __builtin_bit_cast(float, (unsigned)u << 16);
}

// =============== K1: router (blocks 0..63) + W1 convert (64..4159) ==========
// W1 convert: src[E][512][2048] f32 -> W1t tiled [E][N/16][K/32][512] bf16,
// tile elem = n_local*32 + k_local (R4 no-LDS form, transpose via loads).
__global__ __launch_bounds__(256) void pre_k(
    const float* __restrict__ x, const float* __restrict__ Wg,
    const float* __restrict__ W1, ushort_t* __restrict__ xbf,
    int* __restrict__ counts, int* __restrict__ ltok, float* __restrict__ lw,
    float* __restrict__ s1, float* __restrict__ s2, float* __restrict__ out,
    ushort_t* __restrict__ W1t) {
  int bid = blockIdx.x;
  int t = threadIdx.x;
  if (bid >= 64) {
    // ---- W1 conversion ----
    int idx = bid - 64;
    int bx = idx & 255, e = idx >> 8;
    int bn = bx & 31, bk = bx >> 5;      /* N=2048 -> 32 bn; K=512 -> 8 bk */
    const int K = DIM, N = HID;
    int w = t >> 6, l = t & 63;
    int n = bn * 64 + l;
    int k_base = bk * 64, kt0 = k_base >> 5, kk = w * 8;
    const float* sp = W1 + ((size_t)e * K + k_base + kk) * N + n;
    float v[16];
#pragma unroll
    for (int j = 0; j < 8; j++) v[j] = sp[(size_t)j * N];
#pragma unroll
    for (int j = 0; j < 8; j++) v[8 + j] = sp[(size_t)(32 + j) * N];
    size_t tb = ((size_t)(e * (N >> 4) + (n >> 4)) * (K >> 5) + kt0) * 512 +
                (n & 15) * 32 + kk;
    union { ushort_t u[8]; uint4 q; } s0, s1u;
#pragma unroll
    for (int j = 0; j < 8; j++) { s0.u[j] = f2b(v[j]); s1u.u[j] = f2b(v[8 + j]); }
    *(uint4*)(W1t + tb) = s0.q;
    *(uint4*)(W1t + tb + 512) = s1u.q;
    return;
  }

  // ---- router ----
  {
    float4 z = {0.f, 0.f, 0.f, 0.f};
    float4* o4 = (float4*)out + bid * 4096 + t;
#pragma unroll
    for (int i = 0; i < 16; i++) o4[i * 256] = z;
  }
  {
    int idx = bid * 256 + t;
    if (idx < NROWS) { s1[idx] = 0.f; s2[idx] = 0.f; }
  }

  __shared__ float xs[4][512];
  __shared__ float lg[4][16];
  __shared__ int lcnt[NEXP];
  __shared__ int ltoks[NEXP][64];
  __shared__ float lws[NEXP][64];
  __shared__ int base_s[NEXP];

  if (t < NEXP) lcnt[t] = 0;
  __syncthreads();

  int lane = t & 63, w = t >> 6;
  int dq = lane >> 2, e4 = lane & 3;
  const float* wgp = Wg + dq * NEXP + e4 * 4;

  for (int it = 0; it < 8; it++) {
    int tok = bid * 32 + w * 8 + it;
    const float* xr = x + (size_t)tok * DIM + lane * 8;
    float4 xa = *(const float4*)xr;
    float4 xb = *(const float4*)(xr + 4);
    union { ushort_t u[8]; uint4 v; } pk;
    pk.u[0] = f2b(xa.x); pk.u[1] = f2b(xa.y); pk.u[2] = f2b(xa.z); pk.u[3] = f2b(xa.w);
    pk.u[4] = f2b(xb.x); pk.u[5] = f2b(xb.y); pk.u[6] = f2b(xb.z); pk.u[7] = f2b(xb.w);
    *(uint4*)(xbf + (size_t)tok * DIM + lane * 8) = pk.v;
    *(float4*)&xs[w][lane * 8] = xa;
    *(float4*)&xs[w][lane * 8 + 4] = xb;

    float4 a = {0.f, 0.f, 0.f, 0.f};
#pragma unroll
    for (int kk = 0; kk < 32; kk++) {
      float xv = xs[w][kk * 16 + dq];
      float4 g = *(const float4*)(wgp + kk * 16 * NEXP);
      a.x += xv * g.x; a.y += xv * g.y; a.z += xv * g.z; a.w += xv * g.w;
    }
#pragma unroll
    for (int off = 32; off >= 4; off >>= 1) {
      a.x += __shfl_down(a.x, off);
      a.y += __shfl_down(a.y, off);
      a.z += __shfl_down(a.z, off);
      a.w += __shfl_down(a.w, off);
    }
    if (lane < 4) *(float4*)&lg[w][lane * 4] = a;
    if (lane == 0) {
      int i0 = 0;
      float v0 = lg[w][0];
#pragma unroll
      for (int e = 1; e < NEXP; e++)
        if (lg[w][e] > v0) { v0 = lg[w][e]; i0 = e; }
      int i1 = -1;
      float v1 = -3.4e38f;
#pragma unroll
      for (int e = 0; e < NEXP; e++)
        if (e != i0 && lg[w][e] > v1) { v1 = lg[w][e]; i1 = e; }
      float ex = __expf(v1 - v0);
      float w0 = 1.f / (1.f + ex);
      int p0 = atomicAdd(&lcnt[i0], 1);
      ltoks[i0][p0] = tok;
      lws[i0][p0] = w0;
      int p1 = atomicAdd(&lcnt[i1], 1);
      ltoks[i1][p1] = tok;
      lws[i1][p1] = ex / (1.f + ex);
    }
  }
  __syncthreads();
  if (t < NEXP) base_s[t] = atomicAdd(&counts[t], lcnt[t]);
  __syncthreads();
  int e = t >> 4, i0 = t & 15;
  int n = lcnt[e], b = base_s[e];
  for (int i = i0; i < n; i += 16) {
    int slot = b + i;
    if (slot < CAP) {
      ltok[e * CAP + slot] = ltoks[e][i];
      lw[e * CAP + slot] = lws[e][i];
    }
  }
}

// ====== K2: ffn1 (blocks 0..639, R4 form) + W2 convert (640..4735) ==========
// ffn1: h = silu(x @ W1 + b1) -> hbuf row-major bf16 + row stats.
// W1t tiled [E][HID/16][DIM/32][512]; frag = base + nb*8192 + ks*512 + ...
__global__ __launch_bounds__(256) void mid_k(
    const ushort_t* __restrict__ W1t, const float* __restrict__ b1,
    const int* __restrict__ counts, const int* __restrict__ ltok,
    const ushort_t* __restrict__ xbf, ushort_t* __restrict__ hbuf,
    float* __restrict__ s1, float* __restrict__ s2,
    const float* __restrict__ W2, ushort_t* __restrict__ W2t) {
  int bid = blockIdx.x;
  int t = threadIdx.x;
  if (bid >= 640) {
    // ---- W2 conversion ----
    int idx = bid - 640;
    int bx = idx & 255, e = idx >> 8;
    int bn = bx & 7, bk = bx >> 3;       /* N=512 -> 8 bn; K=2048 -> 32 bk */
    const int K = HID, N = DIM;
    int w = t >> 6, l = t & 63;
    int n = bn * 64 + l;
    int k_base = bk * 64, kt0 = k_base >> 5, kk = w * 8;
    const float* sp = W2 + ((size_t)e * K + k_base + kk) * N + n;
    float v[16];
#pragma unroll
    for (int j = 0; j < 8; j++) v[j] = sp[(size_t)j * N];
#pragma unroll
    for (int j = 0; j < 8; j++) v[8 + j] = sp[(size_t)(32 + j) * N];
    size_t tb = ((size_t)(e * (N >> 4) + (n >> 4)) * (K >> 5) + kt0) * 512 +
                (n & 15) * 32 + kk;
    union { ushort_t u[8]; uint4 q; } s0, s1u;
#pragma unroll
    for (int j = 0; j < 8; j++) { s0.u[j] = f2b(v[j]); s1u.u[j] = f2b(v[8 + j]); }
    *(uint4*)(W2t + tb) = s0.q;
    *(uint4*)(W2t + tb + 512) = s1u.q;
    return;
  }

  // ---- ffn1 ----
  int xb = bid % 80;
  int e = xb / NTPE, mt = xb % NTPE;
  int cnt = counts[e];
  if (cnt - mt * 64 <= 0) return;
  int row0 = e * CAP + mt * 64;
  int h0 = (bid / 80) * 256;

  __shared__ __align__(16) ushort_t As[2][64 * 40];

  int lane = t & 63, wave = t >> 6;
  int quad = lane >> 4, l16 = lane & 15;

  int sr = t >> 2, sp = t & 3;
  int stok = ltok[row0 + sr];
  bool sok = (unsigned)stok < TOKENS;
  const ushort_t* sx = xbf + (size_t)(sok ? stok : 0) * DIM + sp * 8;

  int ncol = h0 + wave * 64 + l16;
  const ushort_t* bb = W1t +
      ((size_t)(e * 128 + (h0 >> 4) + wave * 4) * 16) * 512 + l16 * 32 + quad * 8;

  f32x4 acc[4][4];
#pragma unroll
  for (int a = 0; a < 4; a++)
#pragma unroll
    for (int b = 0; b < 4; b++) acc[a][b] = {0.f, 0.f, 0.f, 0.f};

  // prologue: A(0) -> LDS[0], A(1) in regs, B(0) in regs
  uint4 avB = {0u, 0u, 0u, 0u};
  {
    uint4 avA = {0u, 0u, 0u, 0u};
    if (sok) {
      avA = *(const uint4*)(sx);
      avB = *(const uint4*)(sx + 32);
    }
    *(uint4*)(&As[0][sr * 40 + sp * 8]) = avA;
  }
  bf16x8 bc[4];
#pragma unroll
  for (int nb = 0; nb < 4; nb++)
    bc[nb] = *(const bf16x8*)(bb + nb * 8192);

#pragma unroll
  for (int ks = 0; ks < 16; ks++) {
    __syncthreads();  // LDS[ks&1] ready
    bf16x8 bn[4];
    if (ks < 15) {
#pragma unroll
      for (int nb = 0; nb < 4; nb++)
        bn[nb] = *(const bf16x8*)(bb + nb * 8192 + (ks + 1) * 512);
    }
    uint4 avN = {0u, 0u, 0u, 0u};
    if (ks < 14 && sok) avN = *(const uint4*)(sx + (ks + 2) * 32);

    bf16x8 af[4];
#pragma unroll
    for (int mb = 0; mb < 4; mb++)
      af[mb] = *(const bf16x8*)(&As[ks & 1][(mb * 16 + l16) * 40 + quad * 8]);
#pragma unroll
    for (int mb = 0; mb < 4; mb++)
#pragma unroll
      for (int nb = 0; nb < 4; nb++)
        acc[mb][nb] = __builtin_amdgcn_mfma_f32_16x16x32_bf16(af[mb], bc[nb], acc[mb][nb], 0, 0, 0);

    if (ks < 15) {
      *(uint4*)(&As[(ks + 1) & 1][sr * 40 + sp * 8]) = avB;
      avB = avN;
#pragma unroll
      for (int nb = 0; nb < 4; nb++) bc[nb] = bn[nb];
    }
  }

  float bia[4];
#pragma unroll
  for (int nb = 0; nb < 4; nb++) bia[nb] = b1[e * HID + ncol + nb * 16];
#pragma unroll
  for (int mb = 0; mb < 4; mb++) {
#pragma unroll
    for (int i = 0; i < 4; i++) {
      int m = mb * 16 + quad * 4 + i;
      size_t rowg = (size_t)(row0 + m);
      float ps = 0.f, qs = 0.f;
#pragma unroll
      for (int nb = 0; nb < 4; nb++) {
        float v = acc[mb][nb][i] + bia[nb];
        v = v / (1.f + __expf(-v));
        hbuf[rowg * HID + ncol + nb * 16] = f2b(v);
        ps += v;
        qs += v * v;
      }
      ps += __shfl_down(ps, 8); qs += __shfl_down(qs, 8);
      ps += __shfl_down(ps, 4); qs += __shfl_down(qs, 4);
      ps += __shfl_down(ps, 2); qs += __shfl_down(qs, 2);
      ps += __shfl_down(ps, 1); qs += __shfl_down(qs, 1);
      if (l16 == 0) {
        atomicAdd(&s1[rowg], ps);
        atomicAdd(&s2[rowg], qs);
      }
    }
  }
}

// ---------------- GEMM2: out[t] += w * (LN(h) @ W2 + b2) --------------------
// R7 z=2 form + expert->XCD pinning swizzle: flat 320-block grid;
// xcd = bid&7, e = (bid>>3)/20*8 + xcd  => all 20 blocks of expert e
// (5 mt x 2 n x 2 z) land on XCD e%8, so the 2MB W2t slice + 1.3MB hbuf
// slice are fetched ~once per XCD L2 instead of ~5x.
__global__ __launch_bounds__(256) void ffn2_k(
    const ushort_t* __restrict__ W2t, const float* __restrict__ b2,
    const float* __restrict__ lng, const float* __restrict__ lnb,
    const int* __restrict__ counts, const int* __restrict__ ltok,
    const float* __restrict__ lw, const ushort_t* __restrict__ hbuf,
    const float* __restrict__ s1, const float* __restrict__ s2,
    float* __restrict__ out) {
  int bid = blockIdx.x;
  int xcd = bid & 7, j = bid >> 3;      /* j in [0,40) */
  int eh = j / 20, r = j % 20;          /* 2 experts per XCD */
  int e = (eh << 3) | xcd;
  int mt = r >> 2, yz = r & 3;
  int n0 = (yz >> 1) * 256;
  int z = yz & 1;
  int kbeg = z * (HID / 2);

  int cnt = counts[e];
  int valid = cnt - mt * 64;
  if (valid <= 0) return;
  valid = valid > 64 ? 64 : valid;
  int row0 = e * CAP + mt * 64;

  __shared__ __align__(16) ushort_t As[2][64 * 40];
  __shared__ float Gs[1024];
  __shared__ float Cs[1024];

  int t = threadIdx.x;
  int lane = t & 63, wave = t >> 6;
  int quad = lane >> 4, l16 = lane & 15;

  // stage gamma/beta slice once
  *(float4*)&Gs[t * 4] = *(const float4*)(lng + (size_t)e * HID + kbeg + t * 4);
  *(float4*)&Cs[t * 4] = *(const float4*)(lnb + (size_t)e * HID + kbeg + t * 4);

  int sr = t >> 2, sp = t & 3;
  size_t srow = (size_t)(row0 + sr);
  const ushort_t* hr = hbuf + srow * HID + kbeg + sp * 8;
  float smu = s1[srow] * (1.f / HID);
  float var = s2[srow] * (1.f / HID) - smu * smu;
  float srs = rsqrtf(var + 1e-5f);

  int ncol = n0 + wave * 64 + l16;
  const ushort_t* bb = W2t +
      ((size_t)(e * 32 + (n0 >> 4) + wave * 4) * 64 + z * 32) * 512 +
      l16 * 32 + quad * 8;

  f32x4 acc[4][4];
#pragma unroll
  for (int a = 0; a < 4; a++)
#pragma unroll
    for (int b = 0; b < 4; b++) acc[a][b] = {0.f, 0.f, 0.f, 0.f};

  uint4 hvA = *(const uint4*)(hr);
  uint4 hvB = *(const uint4*)(hr + 32);
  __syncthreads();  // Gs/Cs ready

  // process step0 -> LDS[0]
  {
    union { uint4 v; ushort_t u[8]; } hv;
    hv.v = hvA;
    int sb = sp * 8;
    union { ushort_t u[8]; uint4 v; } pk;
#pragma unroll
    for (int jj = 0; jj < 8; jj++) {
      float f = (b2f(hv.u[jj]) - smu) * srs;
      pk.u[jj] = f2b(f * Gs[sb + jj] + Cs[sb + jj]);
    }
    *(uint4*)(&As[0][sr * 40 + sp * 8]) = pk.v;
  }
  bf16x8 bc[4];
#pragma unroll
  for (int nb = 0; nb < 4; nb++)
    bc[nb] = *(const bf16x8*)(bb + nb * 32768);

#pragma unroll 8
  for (int ks = 0; ks < 32; ks++) {
    __syncthreads();  // LDS[ks&1] ready
    bf16x8 bn[4];
    if (ks < 31) {
#pragma unroll
      for (int nb = 0; nb < 4; nb++)
        bn[nb] = *(const bf16x8*)(bb + nb * 32768 + (ks + 1) * 512);
    }
    uint4 hvN = {0u, 0u, 0u, 0u};
    if (ks < 30) hvN = *(const uint4*)(hr + (ks + 2) * 32);

    bf16x8 af[4];
#pragma unroll
    for (int mb = 0; mb < 4; mb++)
      af[mb] = *(const bf16x8*)(&As[ks & 1][(mb * 16 + l16) * 40 + quad * 8]);
#pragma unroll
    for (int mb = 0; mb < 4; mb++)
#pragma unroll
      for (int nb = 0; nb < 4; nb++)
        acc[mb][nb] = __builtin_amdgcn_mfma_f32_16x16x32_bf16(af[mb], bc[nb], acc[mb][nb], 0, 0, 0);

    if (ks < 31) {
      union { uint4 v; ushort_t u[8]; } hv;
      hv.v = hvB;
      int sb = (ks + 1) * 32 + sp * 8;
      union { ushort_t u[8]; uint4 v; } pk;
#pragma unroll
      for (int jj = 0; jj < 8; jj++) {
        float f = (b2f(hv.u[jj]) - smu) * srs;
        pk.u[jj] = f2b(f * Gs[sb + jj] + Cs[sb + jj]);
      }
      *(uint4*)(&As[(ks + 1) & 1][sr * 40 + sp * 8]) = pk.v;
      hvB = hvN;
#pragma unroll
      for (int nb = 0; nb < 4; nb++) bc[nb] = bn[nb];
    }
  }

  bool addb = (z == 0);
  float bia[4];
#pragma unroll
  for (int nb = 0; nb < 4; nb++)
    bia[nb] = addb ? b2[e * DIM + ncol + nb * 16] : 0.f;
#pragma unroll
  for (int mb = 0; mb < 4; mb++) {
#pragma unroll
    for (int i = 0; i < 4; i++) {
      int m = mb * 16 + quad * 4 + i;
      if (m < valid) {
        int tok = ltok[row0 + m];
        float w = lw[row0 + m];
#pragma unroll
        for (int nb = 0; nb < 4; nb++) {
          float v = acc[mb][nb][i] + bia[nb];
          atomicAdd(out + (size_t)tok * DIM + ncol + nb * 16, w * v);
        }
      }
    }
  }
}

extern "C" void kernel_launch(void* const* d_in, const int* in_sizes, int n_in,
                              void* d_out, int out_size, void* d_ws, size_t ws_size,
                              hipStream_t stream) {
  const float* x = (const float*)d_in[0];
  const float* Wg = (const float*)d_in[1];
  const float* W1 = (const float*)d_in[2];
  const float* b1 = (const float*)d_in[3];
  const float* lng = (const float*)d_in[4];
  const float* lnb = (const float*)d_in[5];
  const float* W2 = (const float*)d_in[6];
  const float* b2 = (const float*)d_in[7];
  float* out = (float*)d_out;

  char* ws = (char*)d_ws;
  int* counts = (int*)(ws + OFF_CNT);
  int* ltok = (int*)(ws + OFF_LTOK);
  float* lw = (float*)(ws + OFF_LW);
  float* s1 = (float*)(ws + OFF_S1);
  float* s2 = (float*)(ws + OFF_S2);
  ushort_t* xbf = (ushort_t*)(ws + OFF_XBF);
  ushort_t* hbuf = (ushort_t*)(ws + OFF_H);
  ushort_t* W1t = (ushort_t*)(ws + OFF_W1T);
  ushort_t* W2t = (ushort_t*)(ws + OFF_W2T);

  hipMemsetAsync(counts, 0, NEXP * sizeof(int), stream);
  pre_k<<<64 + 4096, 256, 0, stream>>>(x, Wg, W1, xbf, counts, ltok, lw,
                                       s1, s2, out, W1t);
  mid_k<<<640 + 4096, 256, 0, stream>>>(W1t, b1, counts, ltok, xbf, hbuf,
                                        s1, s2, W2, W2t);
  ffn2_k<<<320, 256, 0, stream>>>(W2t, b2, lng, lnb, counts, ltok, lw,
                                  hbuf, s1, s2, out);
}

// Round 10
// 238.147 us; speedup vs baseline: 1.1231x; 1.0340x over previous
//
#include <hip/hip_runtime.h>
#include <hip/hip_bf16.h>

#define TOKENS 2048
#define DIM 512
#define NEXP 16
#define HID 2048
#define CAP 320                 /* rows per expert (mean 256, +4 sigma margin) */
#define NTPE (CAP / 64)         /* 5 m-tiles per expert */
#define MTILES (NEXP * NTPE)    /* 80 */
#define NROWS (NEXP * CAP)      /* 5120 */

typedef unsigned short ushort_t;
typedef __attribute__((ext_vector_type(8))) __bf16 bf16x8;
typedef __attribute__((ext_vector_type(4))) float f32x4;

// workspace byte offsets (total 90,260,480 <= known-good 90.3MB)
#define OFF_CNT 0
#define OFF_LTOK 1024
#define OFF_LW 21504
#define OFF_S1 41984
#define OFF_S2 62464
#define OFF_XBF 82944        /* 2048*512*2 = 2,097,152 -> ends 2,180,096 */
#define OFF_H 2180096        /* 5120*2048*2 = 20,971,520 -> ends 23,151,616 */
#define OFF_W1T 23151616     /* 33,554,432 -> ends 56,706,048 */
#define OFF_W2T 56706048     /* 33,554,432 -> ends 90,260,480 */

__device__ __forceinline__ ushort_t f2b(float f) {
  __bf16 b = (__bf16)f;
  return __builtin_bit_cast(unsigned short, b);
}
__device__ __forceinline__ float b2f(ushort_t u) {
  return __builtin_bit_cast(float, (unsigned)u << 16);
}

// Expert->XCD affinity rule used by EVERY phase: expert e runs on XCD (e&7).
// W1t/W2t/hbuf are expert-major, so producer and consumer of an expert's
// slices share one XCD L2 (2 experts x ~2MB fits the 4MB L2).
// f32 weight streams (read-once) use nontemporal loads to avoid evicting
// the reusable expert slices.

// =============== K1: router (blocks 0..63) + W1 convert (64..4159) ==========
// W1 convert: src[E][512][2048] f32 -> W1t tiled [E][N/16][K/32][512] bf16,
// tile elem = n_local*32 + k_local (R4 no-LDS form, transpose via loads).
__global__ __launch_bounds__(256) void pre_k(
    const float* __restrict__ x, const float* __restrict__ Wg,
    const float* __restrict__ W1, ushort_t* __restrict__ xbf,
    int* __restrict__ counts, int* __restrict__ ltok, float* __restrict__ lw,
    float* __restrict__ s1, float* __restrict__ s2, float* __restrict__ out,
    ushort_t* __restrict__ W1t) {
  int bid = blockIdx.x;
  int t = threadIdx.x;
  if (bid >= 64) {
    // ---- W1 conversion (expert->XCD pinned: e&7 == idx&7) ----
    int idx = bid - 64;
    int xcd = idx & 7;
    int j = idx >> 3;                    /* [0,512) */
    int e = ((j >> 8) << 3) | xcd;       /* 2 experts per XCD */
    int bx = j & 255;
    int bn = bx & 31, bk = bx >> 5;      /* N=2048 -> 32 bn; K=512 -> 8 bk */
    const int K = DIM, N = HID;
    int w = t >> 6, l = t & 63;
    int n = bn * 64 + l;
    int k_base = bk * 64, kt0 = k_base >> 5, kk = w * 8;
    const float* sp = W1 + ((size_t)e * K + k_base + kk) * N + n;
    float v[16];
#pragma unroll
    for (int jj = 0; jj < 8; jj++)
      v[jj] = __builtin_nontemporal_load(sp + (size_t)jj * N);
#pragma unroll
    for (int jj = 0; jj < 8; jj++)
      v[8 + jj] = __builtin_nontemporal_load(sp + (size_t)(32 + jj) * N);
    size_t tb = ((size_t)(e * (N >> 4) + (n >> 4)) * (K >> 5) + kt0) * 512 +
                (n & 15) * 32 + kk;
    union { ushort_t u[8]; uint4 q; } s0, s1u;
#pragma unroll
    for (int jj = 0; jj < 8; jj++) { s0.u[jj] = f2b(v[jj]); s1u.u[jj] = f2b(v[8 + jj]); }
    *(uint4*)(W1t + tb) = s0.q;
    *(uint4*)(W1t + tb + 512) = s1u.q;
    return;
  }

  // ---- router ----
  {
    float4 z = {0.f, 0.f, 0.f, 0.f};
    float4* o4 = (float4*)out + bid * 4096 + t;
#pragma unroll
    for (int i = 0; i < 16; i++) o4[i * 256] = z;
  }
  {
    int idx = bid * 256 + t;
    if (idx < NROWS) { s1[idx] = 0.f; s2[idx] = 0.f; }
  }

  __shared__ float xs[4][512];
  __shared__ float lg[4][16];
  __shared__ int lcnt[NEXP];
  __shared__ int ltoks[NEXP][64];
  __shared__ float lws[NEXP][64];
  __shared__ int base_s[NEXP];

  if (t < NEXP) lcnt[t] = 0;
  __syncthreads();

  int lane = t & 63, w = t >> 6;
  int dq = lane >> 2, e4 = lane & 3;
  const float* wgp = Wg + dq * NEXP + e4 * 4;

  for (int it = 0; it < 8; it++) {
    int tok = bid * 32 + w * 8 + it;
    const float* xr = x + (size_t)tok * DIM + lane * 8;
    float4 xa = *(const float4*)xr;
    float4 xb = *(const float4*)(xr + 4);
    union { ushort_t u[8]; uint4 v; } pk;
    pk.u[0] = f2b(xa.x); pk.u[1] = f2b(xa.y); pk.u[2] = f2b(xa.z); pk.u[3] = f2b(xa.w);
    pk.u[4] = f2b(xb.x); pk.u[5] = f2b(xb.y); pk.u[6] = f2b(xb.z); pk.u[7] = f2b(xb.w);
    *(uint4*)(xbf + (size_t)tok * DIM + lane * 8) = pk.v;
    *(float4*)&xs[w][lane * 8] = xa;
    *(float4*)&xs[w][lane * 8 + 4] = xb;

    float4 a = {0.f, 0.f, 0.f, 0.f};
#pragma unroll
    for (int kk = 0; kk < 32; kk++) {
      float xv = xs[w][kk * 16 + dq];
      float4 g = *(const float4*)(wgp + kk * 16 * NEXP);
      a.x += xv * g.x; a.y += xv * g.y; a.z += xv * g.z; a.w += xv * g.w;
    }
#pragma unroll
    for (int off = 32; off >= 4; off >>= 1) {
      a.x += __shfl_down(a.x, off);
      a.y += __shfl_down(a.y, off);
      a.z += __shfl_down(a.z, off);
      a.w += __shfl_down(a.w, off);
    }
    if (lane < 4) *(float4*)&lg[w][lane * 4] = a;
    if (lane == 0) {
      int i0 = 0;
      float v0 = lg[w][0];
#pragma unroll
      for (int e = 1; e < NEXP; e++)
        if (lg[w][e] > v0) { v0 = lg[w][e]; i0 = e; }
      int i1 = -1;
      float v1 = -3.4e38f;
#pragma unroll
      for (int e = 0; e < NEXP; e++)
        if (e != i0 && lg[w][e] > v1) { v1 = lg[w][e]; i1 = e; }
      float ex = __expf(v1 - v0);
      float w0 = 1.f / (1.f + ex);
      int p0 = atomicAdd(&lcnt[i0], 1);
      ltoks[i0][p0] = tok;
      lws[i0][p0] = w0;
      int p1 = atomicAdd(&lcnt[i1], 1);
      ltoks[i1][p1] = tok;
      lws[i1][p1] = ex / (1.f + ex);
    }
  }
  __syncthreads();
  if (t < NEXP) base_s[t] = atomicAdd(&counts[t], lcnt[t]);
  __syncthreads();
  int e = t >> 4, i0 = t & 15;
  int n = lcnt[e], b = base_s[e];
  for (int i = i0; i < n; i += 16) {
    int slot = b + i;
    if (slot < CAP) {
      ltok[e * CAP + slot] = ltoks[e][i];
      lw[e * CAP + slot] = lws[e][i];
    }
  }
}

// ====== K2: ffn1 (blocks 0..639) + W2 convert (640..4735), both pinned =====
// ffn1: h = silu(x @ W1 + b1) -> hbuf row-major bf16 + row stats.
// W1t tiled [E][HID/16][DIM/32][512]; frag = base + nb*8192 + ks*512 + ...
__global__ __launch_bounds__(256) void mid_k(
    const ushort_t* __restrict__ W1t, const float* __restrict__ b1,
    const int* __restrict__ counts, const int* __restrict__ ltok,
    const ushort_t* __restrict__ xbf, ushort_t* __restrict__ hbuf,
    float* __restrict__ s1, float* __restrict__ s2,
    const float* __restrict__ W2, ushort_t* __restrict__ W2t) {
  int bid = blockIdx.x;
  int t = threadIdx.x;
  if (bid >= 640) {
    // ---- W2 conversion (expert->XCD pinned: e&7 == idx&7) ----
    int idx = bid - 640;
    int xcd = idx & 7;
    int j = idx >> 3;                    /* [0,512) */
    int e = ((j >> 8) << 3) | xcd;       /* 2 experts per XCD */
    int bx = j & 255;
    int bn = bx & 7, bk = bx >> 3;       /* N=512 -> 8 bn; K=2048 -> 32 bk */
    const int K = HID, N = DIM;
    int w = t >> 6, l = t & 63;
    int n = bn * 64 + l;
    int k_base = bk * 64, kt0 = k_base >> 5, kk = w * 8;
    const float* sp = W2 + ((size_t)e * K + k_base + kk) * N + n;
    float v[16];
#pragma unroll
    for (int jj = 0; jj < 8; jj++)
      v[jj] = __builtin_nontemporal_load(sp + (size_t)jj * N);
#pragma unroll
    for (int jj = 0; jj < 8; jj++)
      v[8 + jj] = __builtin_nontemporal_load(sp + (size_t)(32 + jj) * N);
    size_t tb = ((size_t)(e * (N >> 4) + (n >> 4)) * (K >> 5) + kt0) * 512 +
                (n & 15) * 32 + kk;
    union { ushort_t u[8]; uint4 q; } s0, s1u;
#pragma unroll
    for (int jj = 0; jj < 8; jj++) { s0.u[jj] = f2b(v[jj]); s1u.u[jj] = f2b(v[8 + jj]); }
    *(uint4*)(W2t + tb) = s0.q;
    *(uint4*)(W2t + tb + 512) = s1u.q;
    return;
  }

  // ---- ffn1 (expert->XCD pinned: e&7 == bid&7) ----
  int xcd = bid & 7;
  int j = bid >> 3;                      /* [0,80) */
  int e = ((j / 40) << 3) | xcd;         /* 2 experts per XCD */
  int r = j % 40;                        /* 5 mt x 8 y */
  int mt = r >> 3;
  int h0 = (r & 7) * 256;
  int cnt = counts[e];
  if (cnt - mt * 64 <= 0) return;
  int row0 = e * CAP + mt * 64;

  __shared__ __align__(16) ushort_t As[2][64 * 40];

  int lane = t & 63, wave = t >> 6;
  int quad = lane >> 4, l16 = lane & 15;

  int sr = t >> 2, sp = t & 3;
  int stok = ltok[row0 + sr];
  bool sok = (unsigned)stok < TOKENS;
  const ushort_t* sx = xbf + (size_t)(sok ? stok : 0) * DIM + sp * 8;

  int ncol = h0 + wave * 64 + l16;
  const ushort_t* bb = W1t +
      ((size_t)(e * 128 + (h0 >> 4) + wave * 4) * 16) * 512 + l16 * 32 + quad * 8;

  f32x4 acc[4][4];
#pragma unroll
  for (int a = 0; a < 4; a++)
#pragma unroll
    for (int b = 0; b < 4; b++) acc[a][b] = {0.f, 0.f, 0.f, 0.f};

  // prologue: A(0) -> LDS[0], A(1) in regs, B(0) in regs
  uint4 avB = {0u, 0u, 0u, 0u};
  {
    uint4 avA = {0u, 0u, 0u, 0u};
    if (sok) {
      avA = *(const uint4*)(sx);
      avB = *(const uint4*)(sx + 32);
    }
    *(uint4*)(&As[0][sr * 40 + sp * 8]) = avA;
  }
  bf16x8 bc[4];
#pragma unroll
  for (int nb = 0; nb < 4; nb++)
    bc[nb] = *(const bf16x8*)(bb + nb * 8192);

#pragma unroll
  for (int ks = 0; ks < 16; ks++) {
    __syncthreads();  // LDS[ks&1] ready
    bf16x8 bn[4];
    if (ks < 15) {
#pragma unroll
      for (int nb = 0; nb < 4; nb++)
        bn[nb] = *(const bf16x8*)(bb + nb * 8192 + (ks + 1) * 512);
    }
    uint4 avN = {0u, 0u, 0u, 0u};
    if (ks < 14 && sok) avN = *(const uint4*)(sx + (ks + 2) * 32);

    bf16x8 af[4];
#pragma unroll
    for (int mb = 0; mb < 4; mb++)
      af[mb] = *(const bf16x8*)(&As[ks & 1][(mb * 16 + l16) * 40 + quad * 8]);
#pragma unroll
    for (int mb = 0; mb < 4; mb++)
#pragma unroll
      for (int nb = 0; nb < 4; nb++)
        acc[mb][nb] = __builtin_amdgcn_mfma_f32_16x16x32_bf16(af[mb], bc[nb], acc[mb][nb], 0, 0, 0);

    if (ks < 15) {
      *(uint4*)(&As[(ks + 1) & 1][sr * 40 + sp * 8]) = avB;
      avB = avN;
#pragma unroll
      for (int nb = 0; nb < 4; nb++) bc[nb] = bn[nb];
    }
  }

  float bia[4];
#pragma unroll
  for (int nb = 0; nb < 4; nb++) bia[nb] = b1[e * HID + ncol + nb * 16];
#pragma unroll
  for (int mb = 0; mb < 4; mb++) {
#pragma unroll
    for (int i = 0; i < 4; i++) {
      int m = mb * 16 + quad * 4 + i;
      size_t rowg = (size_t)(row0 + m);
      float ps = 0.f, qs = 0.f;
#pragma unroll
      for (int nb = 0; nb < 4; nb++) {
        float v = acc[mb][nb][i] + bia[nb];
        v = v / (1.f + __expf(-v));
        hbuf[rowg * HID + ncol + nb * 16] = f2b(v);
        ps += v;
        qs += v * v;
      }
      ps += __shfl_down(ps, 8); qs += __shfl_down(qs, 8);
      ps += __shfl_down(ps, 4); qs += __shfl_down(qs, 4);
      ps += __shfl_down(ps, 2); qs += __shfl_down(qs, 2);
      ps += __shfl_down(ps, 1); qs += __shfl_down(qs, 1);
      if (l16 == 0) {
        atomicAdd(&s1[rowg], ps);
        atomicAdd(&s2[rowg], qs);
      }
    }
  }
}

// ---------------- GEMM2: out[t] += w * (LN(h) @ W2 + b2) --------------------
// R9 form: expert->XCD pinned flat 320-block grid; z=2 K-split;
// W2t tiled [E][DIM/16][HID/32][512]; LDS double-buffered pipelined.
__global__ __launch_bounds__(256) void ffn2_k(
    const ushort_t* __restrict__ W2t, const float* __restrict__ b2,
    const float* __restrict__ lng, const float* __restrict__ lnb,
    const int* __restrict__ counts, const int* __restrict__ ltok,
    const float* __restrict__ lw, const ushort_t* __restrict__ hbuf,
    const float* __restrict__ s1, const float* __restrict__ s2,
    float* __restrict__ out) {
  int bid = blockIdx.x;
  int xcd = bid & 7, j = bid >> 3;      /* j in [0,40) */
  int eh = j / 20, r = j % 20;          /* 2 experts per XCD */
  int e = (eh << 3) | xcd;
  int mt = r >> 2, yz = r & 3;
  int n0 = (yz >> 1) * 256;
  int z = yz & 1;
  int kbeg = z * (HID / 2);

  int cnt = counts[e];
  int valid = cnt - mt * 64;
  if (valid <= 0) return;
  valid = valid > 64 ? 64 : valid;
  int row0 = e * CAP + mt * 64;

  __shared__ __align__(16) ushort_t As[2][64 * 40];
  __shared__ float Gs[1024];
  __shared__ float Cs[1024];

  int t = threadIdx.x;
  int lane = t & 63, wave = t >> 6;
  int quad = lane >> 4, l16 = lane & 15;

  // stage gamma/beta slice once
  *(float4*)&Gs[t * 4] = *(const float4*)(lng + (size_t)e * HID + kbeg + t * 4);
  *(float4*)&Cs[t * 4] = *(const float4*)(lnb + (size_t)e * HID + kbeg + t * 4);

  int sr = t >> 2, sp = t & 3;
  size_t srow = (size_t)(row0 + sr);
  const ushort_t* hr = hbuf + srow * HID + kbeg + sp * 8;
  float smu = s1[srow] * (1.f / HID);
  float var = s2[srow] * (1.f / HID) - smu * smu;
  float srs = rsqrtf(var + 1e-5f);

  int ncol = n0 + wave * 64 + l16;
  const ushort_t* bb = W2t +
      ((size_t)(e * 32 + (n0 >> 4) + wave * 4) * 64 + z * 32) * 512 +
      l16 * 32 + quad * 8;

  f32x4 acc[4][4];
#pragma unroll
  for (int a = 0; a < 4; a++)
#pragma unroll
    for (int b = 0; b < 4; b++) acc[a][b] = {0.f, 0.f, 0.f, 0.f};

  uint4 hvA = *(const uint4*)(hr);
  uint4 hvB = *(const uint4*)(hr + 32);
  __syncthreads();  // Gs/Cs ready

  // process step0 -> LDS[0]
  {
    union { uint4 v; ushort_t u[8]; } hv;
    hv.v = hvA;
    int sb = sp * 8;
    union { ushort_t u[8]; uint4 v; } pk;
#pragma unroll
    for (int jj = 0; jj < 8; jj++) {
      float f = (b2f(hv.u[jj]) - smu) * srs;
      pk.u[jj] = f2b(f * Gs[sb + jj] + Cs[sb + jj]);
    }
    *(uint4*)(&As[0][sr * 40 + sp * 8]) = pk.v;
  }
  bf16x8 bc[4];
#pragma unroll
  for (int nb = 0; nb < 4; nb++)
    bc[nb] = *(const bf16x8*)(bb + nb * 32768);

#pragma unroll 8
  for (int ks = 0; ks < 32; ks++) {
    __syncthreads();  // LDS[ks&1] ready
    bf16x8 bn[4];
    if (ks < 31) {
#pragma unroll
      for (int nb = 0; nb < 4; nb++)
        bn[nb] = *(const bf16x8*)(bb + nb * 32768 + (ks + 1) * 512);
    }
    uint4 hvN = {0u, 0u, 0u, 0u};
    if (ks < 30) hvN = *(const uint4*)(hr + (ks + 2) * 32);

    bf16x8 af[4];
#pragma unroll
    for (int mb = 0; mb < 4; mb++)
      af[mb] = *(const bf16x8*)(&As[ks & 1][(mb * 16 + l16) * 40 + quad * 8]);
#pragma unroll
    for (int mb = 0; mb < 4; mb++)
#pragma unroll
      for (int nb = 0; nb < 4; nb++)
        acc[mb][nb] = __builtin_amdgcn_mfma_f32_16x16x32_bf16(af[mb], bc[nb], acc[mb][nb], 0, 0, 0);

    if (ks < 31) {
      union { uint4 v; ushort_t u[8]; } hv;
      hv.v = hvB;
      int sb = (ks + 1) * 32 + sp * 8;
      union { ushort_t u[8]; uint4 v; } pk;
#pragma unroll
      for (int jj = 0; jj < 8; jj++) {
        float f = (b2f(hv.u[jj]) - smu) * srs;
        pk.u[jj] = f2b(f * Gs[sb + jj] + Cs[sb + jj]);
      }
      *(uint4*)(&As[(ks + 1) & 1][sr * 40 + sp * 8]) = pk.v;
      hvB = hvN;
#pragma unroll
      for (int nb = 0; nb < 4; nb++) bc[nb] = bn[nb];
    }
  }

  bool addb = (z == 0);
  float bia[4];
#pragma unroll
  for (int nb = 0; nb < 4; nb++)
    bia[nb] = addb ? b2[e * DIM + ncol + nb * 16] : 0.f;
#pragma unroll
  for (int mb = 0; mb < 4; mb++) {
#pragma unroll
    for (int i = 0; i < 4; i++) {
      int m = mb * 16 + quad * 4 + i;
      if (m < valid) {
        int tok = ltok[row0 + m];
        float w = lw[row0 + m];
#pragma unroll
        for (int nb = 0; nb < 4; nb++) {
          float v = acc[mb][nb][i] + bia[nb];
          atomicAdd(out + (size_t)tok * DIM + ncol + nb * 16, w * v);
        }
      }
    }
  }
}

extern "C" void kernel_launch(void* const* d_in, const int* in_sizes, int n_in,
                              void* d_out, int out_size, void* d_ws, size_t ws_size,
                              hipStream_t stream) {
  const float* x = (const float*)d_in[0];
  const float* Wg = (const float*)d_in[1];
  const float* W1 = (const float*)d_in[2];
  const float* b1 = (const float*)d_in[3];
  const float* lng = (const float*)d_in[4];
  const float* lnb = (const float*)d_in[5];
  const float* W2 = (const float*)d_in[6];
  const float* b2 = (const float*)d_in[7];
  float* out = (float*)d_out;

  char* ws = (char*)d_ws;
  int* counts = (int*)(ws + OFF_CNT);
  int* ltok = (int*)(ws + OFF_LTOK);
  float* lw = (float*)(ws + OFF_LW);
  float* s1 = (float*)(ws + OFF_S1);
  float* s2 = (float*)(ws + OFF_S2);
  ushort_t* xbf = (ushort_t*)(ws + OFF_XBF);
  ushort_t* hbuf = (ushort_t*)(ws + OFF_H);
  ushort_t* W1t = (ushort_t*)(ws + OFF_W1T);
  ushort_t* W2t = (ushort_t*)(ws + OFF_W2T);

  hipMemsetAsync(counts, 0, NEXP * sizeof(int), stream);
  pre_k<<<64 + 4096, 256, 0, stream>>>(x, Wg, W1, xbf, counts, ltok, lw,
                                       s1, s2, out, W1t);
  mid_k<<<640 + 4096, 256, 0, stream>>>(W1t, b1, counts, ltok, xbf, hbuf,
                                        s1, s2, W2, W2t);
  ffn2_k<<<320, 256, 0, stream>>>(W2t, b2, lng, lnb, counts, ltok, lw,
                                  hbuf, s1, s2, out);
}

// Round 11
// 234.692 us; speedup vs baseline: 1.1396x; 1.0147x over previous
//
#include <hip/hip_runtime.h>
#include <hip/hip_bf16.h>

#define TOKENS 2048
#define DIM 512
#define NEXP 16
#define HID 2048
#define CAP 320                 /* rows per expert (mean 256, +4 sigma margin) */
#define NTPE (CAP / 64)         /* 5 m-tiles per expert */
#define MTILES (NEXP * NTPE)    /* 80 */
#define NROWS (NEXP * CAP)      /* 5120 */

typedef unsigned short ushort_t;
typedef __attribute__((ext_vector_type(8))) __bf16 bf16x8;
typedef __attribute__((ext_vector_type(4))) float f32x4;

// workspace byte offsets (total 90,260,480 <= known-good 90.3MB)
#define OFF_CNT 0
#define OFF_LTOK 1024
#define OFF_LW 21504
#define OFF_S1 41984
#define OFF_S2 62464
#define OFF_XBF 82944        /* 2048*512*2 = 2,097,152 -> ends 2,180,096 */
#define OFF_H 2180096        /* 5120*2048*2 = 20,971,520 -> ends 23,151,616 */
#define OFF_W1T 23151616     /* 33,554,432 -> ends 56,706,048 */
#define OFF_W2T 56706048     /* 33,554,432 -> ends 90,260,480 */

__device__ __forceinline__ ushort_t f2b(float f) {
  __bf16 b = (__bf16)f;
  return __builtin_bit_cast(unsigned short, b);
}
__device__ __forceinline__ float b2f(ushort_t u) {
  return __builtin_bit_cast(float, (unsigned)u << 16);
}

// Expert->XCD affinity rule used by EVERY phase: expert e runs on XCD (e&7).
// W1t/W2t/hbuf are expert-major, so producer and consumer of an expert's
// slices share one XCD L2. f32 weight streams use nontemporal loads.

// =============== K1: router (blocks 0..63) + W1 convert (64..4159) ==========
__global__ __launch_bounds__(256) void pre_k(
    const float* __restrict__ x, const float* __restrict__ Wg,
    const float* __restrict__ W1, ushort_t* __restrict__ xbf,
    int* __restrict__ counts, int* __restrict__ ltok, float* __restrict__ lw,
    float* __restrict__ s1, float* __restrict__ s2, float* __restrict__ out,
    ushort_t* __restrict__ W1t) {
  int bid = blockIdx.x;
  int t = threadIdx.x;
  if (bid >= 64) {
    // ---- W1 conversion (expert->XCD pinned: e&7 == idx&7) ----
    int idx = bid - 64;
    int xcd = idx & 7;
    int j = idx >> 3;                    /* [0,512) */
    int e = ((j >> 8) << 3) | xcd;       /* 2 experts per XCD */
    int bx = j & 255;
    int bn = bx & 31, bk = bx >> 5;      /* N=2048 -> 32 bn; K=512 -> 8 bk */
    const int K = DIM, N = HID;
    int w = t >> 6, l = t & 63;
    int n = bn * 64 + l;
    int k_base = bk * 64, kt0 = k_base >> 5, kk = w * 8;
    const float* sp = W1 + ((size_t)e * K + k_base + kk) * N + n;
    float v[16];
#pragma unroll
    for (int jj = 0; jj < 8; jj++)
      v[jj] = __builtin_nontemporal_load(sp + (size_t)jj * N);
#pragma unroll
    for (int jj = 0; jj < 8; jj++)
      v[8 + jj] = __builtin_nontemporal_load(sp + (size_t)(32 + jj) * N);
    size_t tb = ((size_t)(e * (N >> 4) + (n >> 4)) * (K >> 5) + kt0) * 512 +
                (n & 15) * 32 + kk;
    union { ushort_t u[8]; uint4 q; } s0, s1u;
#pragma unroll
    for (int jj = 0; jj < 8; jj++) { s0.u[jj] = f2b(v[jj]); s1u.u[jj] = f2b(v[8 + jj]); }
    *(uint4*)(W1t + tb) = s0.q;
    *(uint4*)(W1t + tb + 512) = s1u.q;
    return;
  }

  // ---- router ----
  {
    float4 z = {0.f, 0.f, 0.f, 0.f};
    float4* o4 = (float4*)out + bid * 4096 + t;
#pragma unroll
    for (int i = 0; i < 16; i++) o4[i * 256] = z;
  }
  {
    int idx = bid * 256 + t;
    if (idx < NROWS) { s1[idx] = 0.f; s2[idx] = 0.f; }
  }

  __shared__ float xs[4][512];
  __shared__ float lg[4][16];
  __shared__ int lcnt[NEXP];
  __shared__ int ltoks[NEXP][64];
  __shared__ float lws[NEXP][64];
  __shared__ int base_s[NEXP];

  if (t < NEXP) lcnt[t] = 0;
  __syncthreads();

  int lane = t & 63, w = t >> 6;
  int dq = lane >> 2, e4 = lane & 3;
  const float* wgp = Wg + dq * NEXP + e4 * 4;

  for (int it = 0; it < 8; it++) {
    int tok = bid * 32 + w * 8 + it;
    const float* xr = x + (size_t)tok * DIM + lane * 8;
    float4 xa = *(const float4*)xr;
    float4 xb = *(const float4*)(xr + 4);
    union { ushort_t u[8]; uint4 v; } pk;
    pk.u[0] = f2b(xa.x); pk.u[1] = f2b(xa.y); pk.u[2] = f2b(xa.z); pk.u[3] = f2b(xa.w);
    pk.u[4] = f2b(xb.x); pk.u[5] = f2b(xb.y); pk.u[6] = f2b(xb.z); pk.u[7] = f2b(xb.w);
    *(uint4*)(xbf + (size_t)tok * DIM + lane * 8) = pk.v;
    *(float4*)&xs[w][lane * 8] = xa;
    *(float4*)&xs[w][lane * 8 + 4] = xb;

    float4 a = {0.f, 0.f, 0.f, 0.f};
#pragma unroll
    for (int kk = 0; kk < 32; kk++) {
      float xv = xs[w][kk * 16 + dq];
      float4 g = *(const float4*)(wgp + kk * 16 * NEXP);
      a.x += xv * g.x; a.y += xv * g.y; a.z += xv * g.z; a.w += xv * g.w;
    }
#pragma unroll
    for (int off = 32; off >= 4; off >>= 1) {
      a.x += __shfl_down(a.x, off);
      a.y += __shfl_down(a.y, off);
      a.z += __shfl_down(a.z, off);
      a.w += __shfl_down(a.w, off);
    }
    if (lane < 4) *(float4*)&lg[w][lane * 4] = a;
    if (lane == 0) {
      int i0 = 0;
      float v0 = lg[w][0];
#pragma unroll
      for (int e = 1; e < NEXP; e++)
        if (lg[w][e] > v0) { v0 = lg[w][e]; i0 = e; }
      int i1 = -1;
      float v1 = -3.4e38f;
#pragma unroll
      for (int e = 0; e < NEXP; e++)
        if (e != i0 && lg[w][e] > v1) { v1 = lg[w][e]; i1 = e; }
      float ex = __expf(v1 - v0);
      float w0 = 1.f / (1.f + ex);
      int p0 = atomicAdd(&lcnt[i0], 1);
      ltoks[i0][p0] = tok;
      lws[i0][p0] = w0;
      int p1 = atomicAdd(&lcnt[i1], 1);
      ltoks[i1][p1] = tok;
      lws[i1][p1] = ex / (1.f + ex);
    }
  }
  __syncthreads();
  if (t < NEXP) base_s[t] = atomicAdd(&counts[t], lcnt[t]);
  __syncthreads();
  int e = t >> 4, i0 = t & 15;
  int n = lcnt[e], b = base_s[e];
  for (int i = i0; i < n; i += 16) {
    int slot = b + i;
    if (slot < CAP) {
      ltok[e * CAP + slot] = ltoks[e][i];
      lw[e * CAP + slot] = lws[e][i];
    }
  }
}

// ====== K2: ffn1 (blocks 0..639) + W2 convert (640..4735), both pinned =====
__global__ __launch_bounds__(256) void mid_k(
    const ushort_t* __restrict__ W1t, const float* __restrict__ b1,
    const int* __restrict__ counts, const int* __restrict__ ltok,
    const ushort_t* __restrict__ xbf, ushort_t* __restrict__ hbuf,
    float* __restrict__ s1, float* __restrict__ s2,
    const float* __restrict__ W2, ushort_t* __restrict__ W2t) {
  int bid = blockIdx.x;
  int t = threadIdx.x;
  if (bid >= 640) {
    // ---- W2 conversion (expert->XCD pinned: e&7 == idx&7) ----
    int idx = bid - 640;
    int xcd = idx & 7;
    int j = idx >> 3;                    /* [0,512) */
    int e = ((j >> 8) << 3) | xcd;       /* 2 experts per XCD */
    int bx = j & 255;
    int bn = bx & 7, bk = bx >> 3;       /* N=512 -> 8 bn; K=2048 -> 32 bk */
    const int K = HID, N = DIM;
    int w = t >> 6, l = t & 63;
    int n = bn * 64 + l;
    int k_base = bk * 64, kt0 = k_base >> 5, kk = w * 8;
    const float* sp = W2 + ((size_t)e * K + k_base + kk) * N + n;
    float v[16];
#pragma unroll
    for (int jj = 0; jj < 8; jj++)
      v[jj] = __builtin_nontemporal_load(sp + (size_t)jj * N);
#pragma unroll
    for (int jj = 0; jj < 8; jj++)
      v[8 + jj] = __builtin_nontemporal_load(sp + (size_t)(32 + jj) * N);
    size_t tb = ((size_t)(e * (N >> 4) + (n >> 4)) * (K >> 5) + kt0) * 512 +
                (n & 15) * 32 + kk;
    union { ushort_t u[8]; uint4 q; } s0, s1u;
#pragma unroll
    for (int jj = 0; jj < 8; jj++) { s0.u[jj] = f2b(v[jj]); s1u.u[jj] = f2b(v[8 + jj]); }
    *(uint4*)(W2t + tb) = s0.q;
    *(uint4*)(W2t + tb + 512) = s1u.q;
    return;
  }

  // ---- ffn1 (expert->XCD pinned: e&7 == bid&7) ----
  int xcd = bid & 7;
  int j = bid >> 3;                      /* [0,80) */
  int e = ((j / 40) << 3) | xcd;         /* 2 experts per XCD */
  int r = j % 40;                        /* 5 mt x 8 y */
  int mt = r >> 3;
  int h0 = (r & 7) * 256;
  int cnt = counts[e];
  if (cnt - mt * 64 <= 0) return;
  int row0 = e * CAP + mt * 64;

  __shared__ __align__(16) ushort_t As[2][64 * 40];

  int lane = t & 63, wave = t >> 6;
  int quad = lane >> 4, l16 = lane & 15;

  int sr = t >> 2, sp = t & 3;
  int stok = ltok[row0 + sr];
  bool sok = (unsigned)stok < TOKENS;
  const ushort_t* sx = xbf + (size_t)(sok ? stok : 0) * DIM + sp * 8;

  int ncol = h0 + wave * 64 + l16;
  const ushort_t* bb = W1t +
      ((size_t)(e * 128 + (h0 >> 4) + wave * 4) * 16) * 512 + l16 * 32 + quad * 8;

  f32x4 acc[4][4];
#pragma unroll
  for (int a = 0; a < 4; a++)
#pragma unroll
    for (int b = 0; b < 4; b++) acc[a][b] = {0.f, 0.f, 0.f, 0.f};

  // prologue: A(0) -> LDS[0], A(1) in regs, B(0) in regs
  uint4 avB = {0u, 0u, 0u, 0u};
  {
    uint4 avA = {0u, 0u, 0u, 0u};
    if (sok) {
      avA = *(const uint4*)(sx);
      avB = *(const uint4*)(sx + 32);
    }
    *(uint4*)(&As[0][sr * 40 + sp * 8]) = avA;
  }
  bf16x8 bc[4];
#pragma unroll
  for (int nb = 0; nb < 4; nb++)
    bc[nb] = *(const bf16x8*)(bb + nb * 8192);

#pragma unroll
  for (int ks = 0; ks < 16; ks++) {
    __syncthreads();  // LDS[ks&1] ready
    bf16x8 bn[4];
    if (ks < 15) {
#pragma unroll
      for (int nb = 0; nb < 4; nb++)
        bn[nb] = *(const bf16x8*)(bb + nb * 8192 + (ks + 1) * 512);
    }
    uint4 avN = {0u, 0u, 0u, 0u};
    if (ks < 14 && sok) avN = *(const uint4*)(sx + (ks + 2) * 32);

    bf16x8 af[4];
#pragma unroll
    for (int mb = 0; mb < 4; mb++)
      af[mb] = *(const bf16x8*)(&As[ks & 1][(mb * 16 + l16) * 40 + quad * 8]);
#pragma unroll
    for (int mb = 0; mb < 4; mb++)
#pragma unroll
      for (int nb = 0; nb < 4; nb++)
        acc[mb][nb] = __builtin_amdgcn_mfma_f32_16x16x32_bf16(af[mb], bc[nb], acc[mb][nb], 0, 0, 0);

    if (ks < 15) {
      *(uint4*)(&As[(ks + 1) & 1][sr * 40 + sp * 8]) = avB;
      avB = avN;
#pragma unroll
      for (int nb = 0; nb < 4; nb++) bc[nb] = bn[nb];
    }
  }

  float bia[4];
#pragma unroll
  for (int nb = 0; nb < 4; nb++) bia[nb] = b1[e * HID + ncol + nb * 16];
#pragma unroll
  for (int mb = 0; mb < 4; mb++) {
#pragma unroll
    for (int i = 0; i < 4; i++) {
      int m = mb * 16 + quad * 4 + i;
      size_t rowg = (size_t)(row0 + m);
      float ps = 0.f, qs = 0.f;
#pragma unroll
      for (int nb = 0; nb < 4; nb++) {
        float v = acc[mb][nb][i] + bia[nb];
        v = v / (1.f + __expf(-v));
        hbuf[rowg * HID + ncol + nb * 16] = f2b(v);
        ps += v;
        qs += v * v;
      }
      ps += __shfl_down(ps, 8); qs += __shfl_down(qs, 8);
      ps += __shfl_down(ps, 4); qs += __shfl_down(qs, 4);
      ps += __shfl_down(ps, 2); qs += __shfl_down(qs, 2);
      ps += __shfl_down(ps, 1); qs += __shfl_down(qs, 1);
      if (l16 == 0) {
        atomicAdd(&s1[rowg], ps);
        atomicAdd(&s2[rowg], qs);
      }
    }
  }
}

// ---------------- GEMM2: out[t] += w * (LN(h) @ W2 + b2) --------------------
// N-split 128 cols/block (acc[4][2]): grid 640 flat blocks pinned to XCDs
// (5/CU capacity vs 2.5 at 256-col). K-loop stays 32 steps z=2 (R8 showed
// K-splitting kills barrier amortization; N-split keeps it).
__global__ __launch_bounds__(256) void ffn2_k(
    const ushort_t* __restrict__ W2t, const float* __restrict__ b2,
    const float* __restrict__ lng, const float* __restrict__ lnb,
    const int* __restrict__ counts, const int* __restrict__ ltok,
    const float* __restrict__ lw, const ushort_t* __restrict__ hbuf,
    const float* __restrict__ s1, const float* __restrict__ s2,
    float* __restrict__ out) {
  int bid = blockIdx.x;
  int xcd = bid & 7, j = bid >> 3;      /* j in [0,80) */
  int eh = j / 40, r = j % 40;          /* 2 experts per XCD */
  int e = (eh << 3) | xcd;
  int mt = r % 5, yz = r / 5;           /* mt fastest: 5 same-slice blocks adjacent */
  int n0 = (yz >> 1) * 128;
  int z = yz & 1;
  int kbeg = z * (HID / 2);

  int cnt = counts[e];
  int valid = cnt - mt * 64;
  if (valid <= 0) return;
  valid = valid > 64 ? 64 : valid;
  int row0 = e * CAP + mt * 64;

  __shared__ __align__(16) ushort_t As[2][64 * 40];
  __shared__ float Gs[1024];
  __shared__ float Cs[1024];

  int t = threadIdx.x;
  int lane = t & 63, wave = t >> 6;
  int quad = lane >> 4, l16 = lane & 15;

  // stage gamma/beta slice once
  *(float4*)&Gs[t * 4] = *(const float4*)(lng + (size_t)e * HID + kbeg + t * 4);
  *(float4*)&Cs[t * 4] = *(const float4*)(lnb + (size_t)e * HID + kbeg + t * 4);

  int sr = t >> 2, sp = t & 3;
  size_t srow = (size_t)(row0 + sr);
  const ushort_t* hr = hbuf + srow * HID + kbeg + sp * 8;
  float smu = s1[srow] * (1.f / HID);
  float var = s2[srow] * (1.f / HID) - smu * smu;
  float srs = rsqrtf(var + 1e-5f);

  int ncol = n0 + wave * 32 + l16;
  const ushort_t* bb = W2t +
      ((size_t)(e * 32 + (n0 >> 4) + wave * 2) * 64 + z * 32) * 512 +
      l16 * 32 + quad * 8;

  f32x4 acc[4][2];
#pragma unroll
  for (int a = 0; a < 4; a++)
#pragma unroll
    for (int b = 0; b < 2; b++) acc[a][b] = {0.f, 0.f, 0.f, 0.f};

  uint4 hvA = *(const uint4*)(hr);
  uint4 hvB = *(const uint4*)(hr + 32);
  __syncthreads();  // Gs/Cs ready

  // process step0 -> LDS[0]
  {
    union { uint4 v; ushort_t u[8]; } hv;
    hv.v = hvA;
    int sb = sp * 8;
    union { ushort_t u[8]; uint4 v; } pk;
#pragma unroll
    for (int jj = 0; jj < 8; jj++) {
      float f = (b2f(hv.u[jj]) - smu) * srs;
      pk.u[jj] = f2b(f * Gs[sb + jj] + Cs[sb + jj]);
    }
    *(uint4*)(&As[0][sr * 40 + sp * 8]) = pk.v;
  }
  bf16x8 bc[2];
#pragma unroll
  for (int nb = 0; nb < 2; nb++)
    bc[nb] = *(const bf16x8*)(bb + nb * 32768);

#pragma unroll 8
  for (int ks = 0; ks < 32; ks++) {
    __syncthreads();  // LDS[ks&1] ready
    bf16x8 bn[2];
    if (ks < 31) {
#pragma unroll
      for (int nb = 0; nb < 2; nb++)
        bn[nb] = *(const bf16x8*)(bb + nb * 32768 + (ks + 1) * 512);
    }
    uint4 hvN = {0u, 0u, 0u, 0u};
    if (ks < 30) hvN = *(const uint4*)(hr + (ks + 2) * 32);

    bf16x8 af[4];
#pragma unroll
    for (int mb = 0; mb < 4; mb++)
      af[mb] = *(const bf16x8*)(&As[ks & 1][(mb * 16 + l16) * 40 + quad * 8]);
#pragma unroll
    for (int mb = 0; mb < 4; mb++)
#pragma unroll
      for (int nb = 0; nb < 2; nb++)
        acc[mb][nb] = __builtin_amdgcn_mfma_f32_16x16x32_bf16(af[mb], bc[nb], acc[mb][nb], 0, 0, 0);

    if (ks < 31) {
      union { uint4 v; ushort_t u[8]; } hv;
      hv.v = hvB;
      int sb = (ks + 1) * 32 + sp * 8;
      union { ushort_t u[8]; uint4 v; } pk;
#pragma unroll
      for (int jj = 0; jj < 8; jj++) {
        float f = (b2f(hv.u[jj]) - smu) * srs;
        pk.u[jj] = f2b(f * Gs[sb + jj] + Cs[sb + jj]);
      }
      *(uint4*)(&As[(ks + 1) & 1][sr * 40 + sp * 8]) = pk.v;
      hvB = hvN;
#pragma unroll
      for (int nb = 0; nb < 2; nb++) bc[nb] = bn[nb];
    }
  }

  bool addb = (z == 0);
  float bia[2];
#pragma unroll
  for (int nb = 0; nb < 2; nb++)
    bia[nb] = addb ? b2[e * DIM + ncol + nb * 16] : 0.f;
#pragma unroll
  for (int mb = 0; mb < 4; mb++) {
#pragma unroll
    for (int i = 0; i < 4; i++) {
      int m = mb * 16 + quad * 4 + i;
      if (m < valid) {
        int tok = ltok[row0 + m];
        float w = lw[row0 + m];
#pragma unroll
        for (int nb = 0; nb < 2; nb++) {
          float v = acc[mb][nb][i] + bia[nb];
          atomicAdd(out + (size_t)tok * DIM + ncol + nb * 16, w * v);
        }
      }
    }
  }
}

extern "C" void kernel_launch(void* const* d_in, const int* in_sizes, int n_in,
                              void* d_out, int out_size, void* d_ws, size_t ws_size,
                              hipStream_t stream) {
  const float* x = (const float*)d_in[0];
  const float* Wg = (const float*)d_in[1];
  const float* W1 = (const float*)d_in[2];
  const float* b1 = (const float*)d_in[3];
  const float* lng = (const float*)d_in[4];
  const float* lnb = (const float*)d_in[5];
  const float* W2 = (const float*)d_in[6];
  const float* b2 = (const float*)d_in[7];
  float* out = (float*)d_out;

  char* ws = (char*)d_ws;
  int* counts = (int*)(ws + OFF_CNT);
  int* ltok = (int*)(ws + OFF_LTOK);
  float* lw = (float*)(ws + OFF_LW);
  float* s1 = (float*)(ws + OFF_S1);
  float* s2 = (float*)(ws + OFF_S2);
  ushort_t* xbf = (ushort_t*)(ws + OFF_XBF);
  ushort_t* hbuf = (ushort_t*)(ws + OFF_H);
  ushort_t* W1t = (ushort_t*)(ws + OFF_W1T);
  ushort_t* W2t = (ushort_t*)(ws + OFF_W2T);

  hipMemsetAsync(counts, 0, NEXP * sizeof(int), stream);
  pre_k<<<64 + 4096, 256, 0, stream>>>(x, Wg, W1, xbf, counts, ltok, lw,
                                       s1, s2, out, W1t);
  mid_k<<<640 + 4096, 256, 0, stream>>>(W1t, b1, counts, ltok, xbf, hbuf,
                                        s1, s2, W2, W2t);
  ffn2_k<<<640, 256, 0, stream>>>(W2t, b2, lng, lnb, counts, ltok, lw,
                                  hbuf, s1, s2, out);
}